// Round 4
// baseline (1315.703 us; speedup 1.0000x reference)
//
#include <hip/hip_runtime.h>

#define N_NODES_C 50000
#define N_EDGES_C 800000
#define N_EDGES2_C (2 * N_EDGES_C)
#define D 128
#define NSHARD 8
#define OFCAP 4096 // overflow list capacity (expected use ~0)

// Bucketed append scheme: BROWS rows per bucket, per-XCD sub-buckets.
#define BROWS 16
#define NBKT (N_NODES_C / BROWS)   // 3125 (exact: 16*3125 = 50000)
#define NSB (NSHARD * NBKT)        // 25000 sub-buckets
#define BCAP 128                   // entries per sub-bucket (mean 64, +8 sigma)

#define GNODES 64
#define LDP 132                                            // pad: multiple of 4 floats
#define GGRID ((N_NODES_C + GNODES - 1) / GNODES)          // 782 gemm blocks
#define FGRID 2048                                         // fill blocks
#define FEPB ((N_EDGES2_C + FGRID - 1) / FGRID)            // 782 edges/block
#define TOTG (GGRID + FGRID)                               // 2830

static __device__ __forceinline__ unsigned short f2bf(float f) {
  unsigned u = __float_as_uint(f);
  u += 0x7fff + ((u >> 16) & 1);  // round-to-nearest-even
  return (unsigned short)(u >> 16);
}
static __device__ __forceinline__ float bf_lo(unsigned u) {
  return __uint_as_float(u << 16);
}
static __device__ __forceinline__ float bf_hi(unsigned u) {
  return __uint_as_float(u & 0xffff0000u);
}

// Physical XCD id (0..7), wave-uniform; steers L2 locality only.
static __device__ __forceinline__ int xcd_id() {
  int v;
  asm volatile("s_getreg_b32 %0, hwreg(HW_REG_XCC_ID, 0, 4)" : "=s"(v));
  return v & (NSHARD - 1);
}

// ---------------------------------------------------------------------------
// Kernel 1: alpha[i] = sigmoid(dot(x[i], alpha_w) + alpha_b), wave per node,
// PLUS zeroing of bcursor[NSB] and ofcnt (adjacent in ws).
// ---------------------------------------------------------------------------
__global__ __launch_bounds__(256) void alpha_zero_kernel(
    const float* __restrict__ x,
    const float* __restrict__ aw,
    const float* __restrict__ ab,
    float* __restrict__ alpha_out,
    float* __restrict__ alpha_ws,
    int* __restrict__ bcursor,   // zeroes [0, NSB + 64) ints (incl ofcnt)
    int n) {
  int gtid = blockIdx.x * blockDim.x + threadIdx.x;
  if (gtid < NSB + 64) bcursor[gtid] = 0;

  int wave = gtid >> 6;
  int lane = threadIdx.x & 63;
  if (wave >= n) return;
  const float* xr = x + (size_t)wave * D;
  float s = xr[lane] * aw[lane] + xr[lane + 64] * aw[lane + 64];
  #pragma unroll
  for (int off = 32; off > 0; off >>= 1)
    s += __shfl_down(s, off);
  if (lane == 0) {
    float a = 1.0f / (1.0f + __expf(-(s + ab[0])));
    alpha_out[wave] = a;
    alpha_ws[wave] = a;
  }
}

// ---------------------------------------------------------------------------
// Kernel 2 (FUSED, block-specialized): GGRID gemm blocks + FGRID fill blocks,
// Bresenham-interleaved.
//
// fill: append (r,c,v-f32) into (xcd, r>>4) sub-bucket. Frontier working set
// per XCD = 3125 lines (~200 KB) with reuse distance ~200 KB — 20x inside L2
// capacity, unlike the per-row cell scheme whose reuse distance equaled its
// 3.2 MB footprint (~= L2) and thrashed: 64 B writeback per 4 B store across
// rounds 1-3 regardless of layout/occupancy/nt (102-112 MB WRITE_SIZE).
// Expected writeback now ~= bytes written (12.8 MB).
// ---------------------------------------------------------------------------
__global__ __launch_bounds__(256) void gemm_fill_kernel(
    const float* __restrict__ x,
    const float* __restrict__ W,
    unsigned* __restrict__ y,        // [N][64] packed words
    const int* __restrict__ lp_rows, const int* __restrict__ lp_cols,
    const float* __restrict__ lp_vals,
    const int* __restrict__ hp_rows, const int* __restrict__ hp_cols,
    const float* __restrict__ hp_vals,
    const float* __restrict__ alpha,
    int* __restrict__ bcursor,       // [NSB], zeroed
    uint2* __restrict__ bins,        // [NSB][BCAP]
    int* __restrict__ ofcnt,
    uint2* __restrict__ ofl,
    int n) {
  __shared__ float zs[GNODES][LDP];  // 33.8 KB
  __shared__ float wt[64][LDP];      // 33.8 KB (one j-half of W)

  int t = threadIdx.x;
  int bid = blockIdx.x;
  // Bresenham role split: exactly GGRID gemm blocks spread evenly.
  int g = (bid * GGRID) / TOTG;
  int gn = ((bid + 1) * GGRID) / TOTG;

  if (gn > g) {
    // ---------------- gemm block: nodes [g*64, g*64+64) ----------------
    int node0 = g * GNODES;
    int tn = t & 15;
    int tjg = t >> 4;   // 0..15
    int jb = tjg * 4;   // local j base within this half

    #pragma unroll
    for (int it = 0; it < 8; ++it) {
      int f = t + it * 256;
      int r = f >> 5;
      int c4 = f & 31;
      int node = node0 + r;
      float4 v = make_float4(0.f, 0.f, 0.f, 0.f);
      if (node < n) v = ((const float4*)(x + (size_t)node * D))[c4];
      *(float4*)&zs[r][c4 * 4] = v;
    }

    for (int jh = 0; jh < 2; ++jh) {
      if (jh) __syncthreads();  // half 0's wt readers done before overwrite
      #pragma unroll
      for (int it = 0; it < 8; ++it) {
        int f = t + it * 256;
        int j = f >> 5;
        int k4 = f & 31;
        *(float4*)&wt[j][k4 * 4] =
            ((const float4*)W)[(size_t)(jh * 64 + j) * 32 + k4];
      }
      __syncthreads();

      float acc[4][4] = {};
      #pragma unroll 2
      for (int k = 0; k < D; k += 4) {
        float4 w0 = *(const float4*)&wt[jb + 0][k];
        float4 w1 = *(const float4*)&wt[jb + 1][k];
        float4 w2 = *(const float4*)&wt[jb + 2][k];
        float4 w3 = *(const float4*)&wt[jb + 3][k];
        float4 z0 = *(const float4*)&zs[tn][k];
        float4 z1 = *(const float4*)&zs[tn + 16][k];
        float4 z2 = *(const float4*)&zs[tn + 32][k];
        float4 z3 = *(const float4*)&zs[tn + 48][k];
        acc[0][0] += z0.x*w0.x + z0.y*w0.y + z0.z*w0.z + z0.w*w0.w;
        acc[0][1] += z0.x*w1.x + z0.y*w1.y + z0.z*w1.z + z0.w*w1.w;
        acc[0][2] += z0.x*w2.x + z0.y*w2.y + z0.z*w2.z + z0.w*w2.w;
        acc[0][3] += z0.x*w3.x + z0.y*w3.y + z0.z*w3.z + z0.w*w3.w;
        acc[1][0] += z1.x*w0.x + z1.y*w0.y + z1.z*w0.z + z1.w*w0.w;
        acc[1][1] += z1.x*w1.x + z1.y*w1.y + z1.z*w1.z + z1.w*w1.w;
        acc[1][2] += z1.x*w2.x + z1.y*w2.y + z1.z*w2.z + z1.w*w2.w;
        acc[1][3] += z1.x*w3.x + z1.y*w3.y + z1.z*w3.z + z1.w*w3.w;
        acc[2][0] += z2.x*w0.x + z2.y*w0.y + z2.z*w0.z + z2.w*w0.w;
        acc[2][1] += z2.x*w1.x + z2.y*w1.y + z2.z*w1.z + z2.w*w1.w;
        acc[2][2] += z2.x*w2.x + z2.y*w2.y + z2.z*w2.z + z2.w*w2.w;
        acc[2][3] += z2.x*w3.x + z2.y*w3.y + z2.z*w3.z + z2.w*w3.w;
        acc[3][0] += z3.x*w0.x + z3.y*w0.y + z3.z*w0.z + z3.w*w0.w;
        acc[3][1] += z3.x*w1.x + z3.y*w1.y + z3.z*w1.z + z3.w*w1.w;
        acc[3][2] += z3.x*w2.x + z3.y*w2.y + z3.z*w2.z + z3.w*w2.w;
        acc[3][3] += z3.x*w3.x + z3.y*w3.y + z3.z*w3.z + z3.w*w3.w;
      }

      #pragma unroll
      for (int ii = 0; ii < 4; ++ii) {
        int node = node0 + ii * 16 + tn;
        if (node < n) {
          uint2 o;
          o.x = (unsigned)f2bf(acc[ii][0]) | ((unsigned)f2bf(acc[ii][1]) << 16);
          o.y = (unsigned)f2bf(acc[ii][2]) | ((unsigned)f2bf(acc[ii][3]) << 16);
          *(uint2*)&y[(size_t)node * 64 + jh * 32 + tjg * 2] = o;
        }
      }
    }
  } else {
    // ---------------- fill block: edges [fb*FEPB, fb*FEPB+FEPB) --------
    int fb = bid - g;
    int xcc = xcd_id();
    int e0 = fb * FEPB;
    int e1 = e0 + FEPB;
    if (e1 > N_EDGES2_C) e1 = N_EDGES2_C;
    for (int e = e0 + t; e < e1; e += 256) {
      int r, c;
      float v;
      if (e < N_EDGES_C) {
        r = __builtin_nontemporal_load(lp_rows + e);
        c = __builtin_nontemporal_load(lp_cols + e);
        v = __builtin_nontemporal_load(lp_vals + e) * alpha[r];
      } else {
        int i = e - N_EDGES_C;
        r = __builtin_nontemporal_load(hp_rows + i);
        c = __builtin_nontemporal_load(hp_cols + i);
        v = __builtin_nontemporal_load(hp_vals + i) * (1.0f - alpha[r]);
      }
      int sb = xcc * NBKT + (r >> 4);
      int p = atomicAdd(&bcursor[sb], 1);
      if (p < BCAP) {
        bins[((size_t)sb << 7) + p] =
            make_uint2(((unsigned)r << 16) | (unsigned)c, __float_as_uint(v));
      } else {
        int q = atomicAdd(ofcnt, 1);
        if (q < OFCAP)
          ofl[q] = make_uint2(((unsigned)r << 16) | (unsigned)c,
                              (unsigned)__float_as_int(v));
      }
    }
  }
}

// ---------------------------------------------------------------------------
// Kernel 3: gather — one block per row-bucket (16 rows). 8 KB LDS f32
// accumulator acc[16][128]; each of the 4 waves drains 2 of the 8 per-XCD
// sub-buckets. Lane owns dims (2l, 2l+1); ds_add_f32 LDS atomics guard
// cross-wave same-row collisions (2-way bank aliasing = free). Dense uniform
// edge loop (no 64-slot overfetch, no ragged per-row tails). 8 KB LDS +
// 256 thr -> 8 blocks/CU (full occupancy for the latency-bound y loads).
// ---------------------------------------------------------------------------
__global__ __launch_bounds__(256) void gather_kernel(
    const int* __restrict__ bcursor,     // [NSB]
    const uint2* __restrict__ bins,      // [NSB][BCAP]
    const unsigned* __restrict__ y,      // [N][64], word q = dims (2q,2q+1)
    const float* __restrict__ bias,
    const int* __restrict__ ofcnt,
    const uint2* __restrict__ ofl,
    float* __restrict__ out) {
  __shared__ float acc[BROWS][D];  // 8 KB
  int t = threadIdx.x;
  int b = blockIdx.x;
  int w = t >> 6;
  int lane = t & 63;

  // zero acc: 2048 floats = 512 float4
  float4* accv = (float4*)acc;
  accv[t] = make_float4(0.f, 0.f, 0.f, 0.f);
  accv[t + 256] = make_float4(0.f, 0.f, 0.f, 0.f);
  __syncthreads();

  #pragma unroll
  for (int si = 0; si < 2; ++si) {
    int sh = w * 2 + si;
    int sb = sh * NBKT + b;
    int ds = bcursor[sb];
    if (ds > BCAP) ds = BCAP;
    const uint2* base = bins + ((size_t)sb << 7);
    for (int h = 0; h < 2; ++h) {
      int off = h * 64;
      int cnt = ds - off;
      if (cnt <= 0) break;
      if (cnt > 64) cnt = 64;
      uint2 wv = base[off + lane];  // coalesced 512 B; >=cnt lanes unused
      int i = 0;
      for (; i + 1 < cnt; i += 2) {
        unsigned x0 = (unsigned)__shfl((int)wv.x, i);
        unsigned f0w = (unsigned)__shfl((int)wv.y, i);
        unsigned x1 = (unsigned)__shfl((int)wv.x, i + 1);
        unsigned f1w = (unsigned)__shfl((int)wv.y, i + 1);
        unsigned u0 = y[(size_t)(x0 & 0xffffu) * 64 + lane];
        unsigned u1 = y[(size_t)(x1 & 0xffffu) * 64 + lane];
        float f0 = __uint_as_float(f0w);
        float f1 = __uint_as_float(f1w);
        int r0 = (x0 >> 16) & (BROWS - 1);
        int r1 = (x1 >> 16) & (BROWS - 1);
        atomicAdd(&acc[r0][2 * lane],     f0 * bf_lo(u0));
        atomicAdd(&acc[r0][2 * lane + 1], f0 * bf_hi(u0));
        atomicAdd(&acc[r1][2 * lane],     f1 * bf_lo(u1));
        atomicAdd(&acc[r1][2 * lane + 1], f1 * bf_hi(u1));
      }
      if (i < cnt) {
        unsigned x0 = (unsigned)__shfl((int)wv.x, i);
        unsigned f0w = (unsigned)__shfl((int)wv.y, i);
        unsigned u0 = y[(size_t)(x0 & 0xffffu) * 64 + lane];
        float f0 = __uint_as_float(f0w);
        int r0 = (x0 >> 16) & (BROWS - 1);
        atomicAdd(&acc[r0][2 * lane],     f0 * bf_lo(u0));
        atomicAdd(&acc[r0][2 * lane + 1], f0 * bf_hi(u0));
      }
    }
  }

  // overflow entries (expected 0): wave 0 only
  if (w == 0) {
    int nof = *ofcnt;
    if (nof > OFCAP) nof = OFCAP;
    for (int i = 0; i < nof; ++i) {
      uint2 o = ofl[i];
      int r = (int)(o.x >> 16);
      if ((r >> 4) == b) {
        unsigned u = y[(size_t)(o.x & 0xffffu) * 64 + lane];
        float v = __int_as_float((int)o.y);
        atomicAdd(&acc[r & (BROWS - 1)][2 * lane],     v * bf_lo(u));
        atomicAdd(&acc[r & (BROWS - 1)][2 * lane + 1], v * bf_hi(u));
      }
    }
  }
  __syncthreads();

  float2 bv = *(const float2*)&bias[lane * 2];
  int row0 = b * BROWS;
  #pragma unroll
  for (int rr = w; rr < BROWS; rr += 4) {
    float2 o;
    o.x = fmaxf(acc[rr][2 * lane]     + bv.x, 0.0f);
    o.y = fmaxf(acc[rr][2 * lane + 1] + bv.y, 0.0f);
    *(float2*)&out[(size_t)(row0 + rr) * D + lane * 2] = o;
  }
}

extern "C" void kernel_launch(void* const* d_in, const int* in_sizes, int n_in,
                              void* d_out, int out_size, void* d_ws, size_t ws_size,
                              hipStream_t stream) {
  const float* x = (const float*)d_in[0];
  const int* lp_rows = (const int*)d_in[1];
  const int* lp_cols = (const int*)d_in[2];
  const float* lp_vals = (const float*)d_in[3];
  const int* hp_rows = (const int*)d_in[4];
  const int* hp_cols = (const int*)d_in[5];
  const float* hp_vals = (const float*)d_in[6];
  const float* alpha_w = (const float*)d_in[7];
  const float* alpha_b = (const float*)d_in[8];
  const float* W = (const float*)d_in[9];
  const float* bias = (const float*)d_in[10];

  float* out = (float*)d_out;                      // [N, 128]
  float* alpha_out = out + (size_t)N_NODES_C * D;  // [N, 1] output tail

  char* ws = (char*)d_ws;
  unsigned* y = (unsigned*)ws;   ws += (size_t)N_NODES_C * 64 * 4;          // 12.8 MB
  float* alpha_ws = (float*)ws;  ws += 200192;
  int* bcursor = (int*)ws;       ws += (size_t)NSB * 4;                     // 100 KB
  int* ofcnt = (int*)ws;         ws += 256;                                 // adjacent to bcursor
  uint2* ofl = (uint2*)ws;       ws += (size_t)OFCAP * 8;                   // 32 KB
  uint2* bins = (uint2*)ws;
  ws += (size_t)NSB * BCAP * 8;                                             // 25.6 MB

  // Dispatch 1: alpha + cursor/ofcnt zeroing
  alpha_zero_kernel<<<(N_NODES_C + 3) / 4, 256, 0, stream>>>(
      x, alpha_w, alpha_b, alpha_out, alpha_ws, bcursor, N_NODES_C);

  // Dispatch 2: block-specialized gemm || fill (bucketed append)
  gemm_fill_kernel<<<TOTG, 256, 0, stream>>>(
      x, W, y,
      lp_rows, lp_cols, lp_vals, hp_rows, hp_cols, hp_vals,
      alpha_ws, bcursor, bins, ofcnt, ofl, N_NODES_C);

  // Dispatch 3: bucketed gather
  gather_kernel<<<NBKT, 256, 0, stream>>>(
      bcursor, bins, (const unsigned*)y, bias, ofcnt, ofl, out);
}

// Round 5
// 271.318 us; speedup vs baseline: 4.8493x; 4.8493x over previous
//
#include <hip/hip_runtime.h>

#define N_NODES_C 50000
#define N_EDGES_C 800000
#define N_EDGES2_C (2 * N_EDGES_C)
#define D 128
#define NSHARD 8
#define SCAP 16    // slots per (shard,row) cell = one 64 B line
#define OFCAP 4096 // overflow list capacity (expected use ~0)
#define CELLW (N_NODES_C * SCAP)  // words per shard region (3.2 MB)

#define GNODES 64
#define LDP 132                                            // pad: multiple of 4 floats (16B-aligned rows)
#define GGRID ((N_NODES_C + GNODES - 1) / GNODES)          // 782 gemm blocks
#define FGRID 2048                                         // fill blocks
#define FEPB ((N_EDGES2_C + FGRID - 1) / FGRID)            // 782 edges/block
#define TOTG (GGRID + FGRID)                               // 2830

static __device__ __forceinline__ unsigned short f2bf(float f) {
  unsigned u = __float_as_uint(f);
  u += 0x7fff + ((u >> 16) & 1);  // round-to-nearest-even
  return (unsigned short)(u >> 16);
}
static __device__ __forceinline__ float bf_lo(unsigned u) {
  return __uint_as_float(u << 16);
}
static __device__ __forceinline__ float bf_hi(unsigned u) {
  return __uint_as_float(u & 0xffff0000u);
}

// Physical XCD id (0..7), wave-uniform; steers L2 locality only.
static __device__ __forceinline__ int xcd_id() {
  int v;
  asm volatile("s_getreg_b32 %0, hwreg(HW_REG_XCC_ID, 0, 4)" : "=s"(v));
  return v & (NSHARD - 1);
}

// ---------------------------------------------------------------------------
// Kernel 1: alpha[i] = sigmoid(dot(x[i], alpha_w) + alpha_b), wave per node,
// PLUS zeroing of rcursor[NSHARD*N] and ofcnt (adjacent in ws) — absorbs the
// hipMemsetAsync dispatch.
// ---------------------------------------------------------------------------
__global__ __launch_bounds__(256) void alpha_zero_kernel(
    const float* __restrict__ x,
    const float* __restrict__ aw,
    const float* __restrict__ ab,
    float* __restrict__ alpha_out,
    float* __restrict__ alpha_ws,
    int* __restrict__ rcursor,   // zeroes [0, NSHARD*N + 64) ints (incl ofcnt)
    int n) {
  int gtid = blockIdx.x * blockDim.x + threadIdx.x;
  if (gtid < NSHARD * N_NODES_C + 64) rcursor[gtid] = 0;

  int wave = gtid >> 6;
  int lane = threadIdx.x & 63;
  if (wave >= n) return;
  const float* xr = x + (size_t)wave * D;
  float s = xr[lane] * aw[lane] + xr[lane + 64] * aw[lane + 64];
  #pragma unroll
  for (int off = 32; off > 0; off >>= 1)
    s += __shfl_down(s, off);
  if (lane == 0) {
    float a = 1.0f / (1.0f + __expf(-(s + ab[0])));
    alpha_out[wave] = a;
    alpha_ws[wave] = a;
  }
}

// ---------------------------------------------------------------------------
// Kernel 2 (FUSED, block-specialized): GGRID gemm blocks + FGRID fill blocks
// in one grid, Bresenham-interleaved so each CU co-hosts a VALU-bound gemm
// block and memory-latency-bound fill blocks. (Round-3 verified body,
// unchanged this round.)
// ---------------------------------------------------------------------------
__global__ __launch_bounds__(256) void gemm_fill_kernel(
    const float* __restrict__ x,
    const float* __restrict__ W,
    unsigned* __restrict__ y,        // [N][64] packed words
    const int* __restrict__ lp_rows, const int* __restrict__ lp_cols,
    const float* __restrict__ lp_vals,
    const int* __restrict__ hp_rows, const int* __restrict__ hp_cols,
    const float* __restrict__ hp_vals,
    const float* __restrict__ alpha,
    int* __restrict__ rcursor,       // [NSHARD][N], zeroed
    unsigned* __restrict__ pairs,    // [NSHARD][N][SCAP]
    int* __restrict__ ofcnt,
    uint2* __restrict__ ofl,
    int n) {
  __shared__ float zs[GNODES][LDP];  // 33.8 KB
  __shared__ float wt[64][LDP];      // 33.8 KB (one j-half of W)

  int t = threadIdx.x;
  int bid = blockIdx.x;
  // Bresenham role split: exactly GGRID gemm blocks spread evenly.
  int g = (bid * GGRID) / TOTG;
  int gn = ((bid + 1) * GGRID) / TOTG;

  if (gn > g) {
    // ---------------- gemm block: nodes [g*64, g*64+64) ----------------
    int node0 = g * GNODES;
    int tn = t & 15;
    int tjg = t >> 4;   // 0..15
    int jb = tjg * 4;   // local j base within this half

    #pragma unroll
    for (int it = 0; it < 8; ++it) {
      int f = t + it * 256;
      int r = f >> 5;
      int c4 = f & 31;
      int node = node0 + r;
      float4 v = make_float4(0.f, 0.f, 0.f, 0.f);
      if (node < n) v = ((const float4*)(x + (size_t)node * D))[c4];
      *(float4*)&zs[r][c4 * 4] = v;
    }

    for (int jh = 0; jh < 2; ++jh) {
      if (jh) __syncthreads();  // half 0's wt readers done before overwrite
      #pragma unroll
      for (int it = 0; it < 8; ++it) {
        int f = t + it * 256;
        int j = f >> 5;
        int k4 = f & 31;
        *(float4*)&wt[j][k4 * 4] =
            ((const float4*)W)[(size_t)(jh * 64 + j) * 32 + k4];
      }
      __syncthreads();

      float acc[4][4] = {};
      #pragma unroll 2
      for (int k = 0; k < D; k += 4) {
        float4 w0 = *(const float4*)&wt[jb + 0][k];
        float4 w1 = *(const float4*)&wt[jb + 1][k];
        float4 w2 = *(const float4*)&wt[jb + 2][k];
        float4 w3 = *(const float4*)&wt[jb + 3][k];
        float4 z0 = *(const float4*)&zs[tn][k];
        float4 z1 = *(const float4*)&zs[tn + 16][k];
        float4 z2 = *(const float4*)&zs[tn + 32][k];
        float4 z3 = *(const float4*)&zs[tn + 48][k];
        acc[0][0] += z0.x*w0.x + z0.y*w0.y + z0.z*w0.z + z0.w*w0.w;
        acc[0][1] += z0.x*w1.x + z0.y*w1.y + z0.z*w1.z + z0.w*w1.w;
        acc[0][2] += z0.x*w2.x + z0.y*w2.y + z0.z*w2.z + z0.w*w2.w;
        acc[0][3] += z0.x*w3.x + z0.y*w3.y + z0.z*w3.z + z0.w*w3.w;
        acc[1][0] += z1.x*w0.x + z1.y*w0.y + z1.z*w0.z + z1.w*w0.w;
        acc[1][1] += z1.x*w1.x + z1.y*w1.y + z1.z*w1.z + z1.w*w1.w;
        acc[1][2] += z1.x*w2.x + z1.y*w2.y + z1.z*w2.z + z1.w*w2.w;
        acc[1][3] += z1.x*w3.x + z1.y*w3.y + z1.z*w3.z + z1.w*w3.w;
        acc[2][0] += z2.x*w0.x + z2.y*w0.y + z2.z*w0.z + z2.w*w0.w;
        acc[2][1] += z2.x*w1.x + z2.y*w1.y + z2.z*w1.z + z2.w*w1.w;
        acc[2][2] += z2.x*w2.x + z2.y*w2.y + z2.z*w2.z + z2.w*w2.w;
        acc[2][3] += z2.x*w3.x + z2.y*w3.y + z2.z*w3.z + z2.w*w3.w;
        acc[3][0] += z3.x*w0.x + z3.y*w0.y + z3.z*w0.z + z3.w*w0.w;
        acc[3][1] += z3.x*w1.x + z3.y*w1.y + z3.z*w1.z + z3.w*w1.w;
        acc[3][2] += z3.x*w2.x + z3.y*w2.y + z3.z*w2.z + z3.w*w2.w;
        acc[3][3] += z3.x*w3.x + z3.y*w3.y + z3.z*w3.z + z3.w*w3.w;
      }

      #pragma unroll
      for (int ii = 0; ii < 4; ++ii) {
        int node = node0 + ii * 16 + tn;
        if (node < n) {
          uint2 o;
          o.x = (unsigned)f2bf(acc[ii][0]) | ((unsigned)f2bf(acc[ii][1]) << 16);
          o.y = (unsigned)f2bf(acc[ii][2]) | ((unsigned)f2bf(acc[ii][3]) << 16);
          *(uint2*)&y[(size_t)node * 64 + jh * 32 + tjg * 2] = o;
        }
      }
    }
  } else {
    // ---------------- fill block: edges [fb*FEPB, fb*FEPB+FEPB) --------
    int fb = bid - g;
    int xcc = xcd_id();
    int e0 = fb * FEPB;
    int e1 = e0 + FEPB;
    if (e1 > N_EDGES2_C) e1 = N_EDGES2_C;
    for (int e = e0 + t; e < e1; e += 256) {
      int r, c;
      float v;
      if (e < N_EDGES_C) {
        r = __builtin_nontemporal_load(lp_rows + e);
        c = __builtin_nontemporal_load(lp_cols + e);
        v = __builtin_nontemporal_load(lp_vals + e) * alpha[r];
      } else {
        int i = e - N_EDGES_C;
        r = __builtin_nontemporal_load(hp_rows + i);
        c = __builtin_nontemporal_load(hp_cols + i);
        v = __builtin_nontemporal_load(hp_vals + i) * (1.0f - alpha[r]);
      }
      int p = atomicAdd(&rcursor[xcc * N_NODES_C + r], 1);
      if (p < SCAP) {
        unsigned pk = (unsigned)c | ((unsigned)f2bf(v) << 16);
        pairs[(size_t)xcc * CELLW + (size_t)r * SCAP + p] = pk;
      } else {
        int q = atomicAdd(ofcnt, 1);
        if (q < OFCAP)
          ofl[q] = make_uint2(((unsigned)r << 16) | (unsigned)c,
                              (unsigned)__float_as_int(v));
      }
    }
  }
}

// ---------------------------------------------------------------------------
// Kernel 3: gather — TWO waves per row; register accumulation, NO atomics
// (round-4 lesson: LDS float atomicAdd = CAS retry loop, 10x regression).
// CHANGE THIS ROUND: the 4 per-cell slot loops are FLATTENED into one
// unified loop over T = ds0+ds1+ds2+ds3 slots (counts are wave-uniform ->
// uniform decode: cell = #(f>=cum), shfl idx = f + off[cell]), processed in
// batches of FOUR independent y-loads (was 2, per-cell) to double memory-
// level parallelism and cut the per-wave dependent-latency chain ~2x.
// ---------------------------------------------------------------------------
__global__ __launch_bounds__(256) void gather_kernel(
    const int* __restrict__ rcursor,     // [NSHARD][N]
    const unsigned* __restrict__ pairs,  // [NSHARD][N][SCAP]
    const unsigned* __restrict__ y,      // [N][64], word q = dims (2q,2q+1)
    const float* __restrict__ bias,
    const int* __restrict__ ofcnt,
    const uint2* __restrict__ ofl,
    float* __restrict__ out) {
  __shared__ float2 part[4][64];
  int t = threadIdx.x;
  int w = t >> 6;      // wave 0..3
  int lane = t & 63;
  int row = blockIdx.x * 2 + (w >> 1);
  int half = w & 1;    // cells [half*4, half*4+4)

  float aL = 0.f, aH = 0.f;
  if (row < N_NODES_C) {
    int mycell = half * 4 + (lane >> 4);
    unsigned wsrc =
        pairs[(size_t)mycell * CELLW + (size_t)row * SCAP + (lane & 15)];

    // wave-uniform per-cell counts -> flattened index decode tables
    int ds0 = rcursor[(size_t)(half * 4 + 0) * N_NODES_C + row];
    int ds1 = rcursor[(size_t)(half * 4 + 1) * N_NODES_C + row];
    int ds2 = rcursor[(size_t)(half * 4 + 2) * N_NODES_C + row];
    int ds3 = rcursor[(size_t)(half * 4 + 3) * N_NODES_C + row];
    if (ds0 > SCAP) ds0 = SCAP;
    if (ds1 > SCAP) ds1 = SCAP;
    if (ds2 > SCAP) ds2 = SCAP;
    if (ds3 > SCAP) ds3 = SCAP;
    int cum0 = ds0;
    int cum1 = cum0 + ds1;
    int cum2 = cum1 + ds2;
    int T = cum2 + ds3;
    int off1 = 16 - cum0;   // idx = f + off[cell]; off0 = 0
    int off2 = 32 - cum1;
    int off3 = 48 - cum2;

    #define SLOT_IDX(f) \
      ((f) + ((f) >= cum2 ? off3 : ((f) >= cum1 ? off2 : ((f) >= cum0 ? off1 : 0))))

    int f = 0;
    for (; f + 3 < T; f += 4) {   // 4 independent y-loads in flight
      unsigned pk0 = (unsigned)__shfl((int)wsrc, SLOT_IDX(f + 0));
      unsigned pk1 = (unsigned)__shfl((int)wsrc, SLOT_IDX(f + 1));
      unsigned pk2 = (unsigned)__shfl((int)wsrc, SLOT_IDX(f + 2));
      unsigned pk3 = (unsigned)__shfl((int)wsrc, SLOT_IDX(f + 3));
      unsigned u0 = y[(size_t)(pk0 & 0xffffu) * 64 + lane];
      unsigned u1 = y[(size_t)(pk1 & 0xffffu) * 64 + lane];
      unsigned u2 = y[(size_t)(pk2 & 0xffffu) * 64 + lane];
      unsigned u3 = y[(size_t)(pk3 & 0xffffu) * 64 + lane];
      float v0 = bf_hi(pk0);
      float v1 = bf_hi(pk1);
      float v2 = bf_hi(pk2);
      float v3 = bf_hi(pk3);
      aL += v0 * bf_lo(u0) + v1 * bf_lo(u1) + v2 * bf_lo(u2) + v3 * bf_lo(u3);
      aH += v0 * bf_hi(u0) + v1 * bf_hi(u1) + v2 * bf_hi(u2) + v3 * bf_hi(u3);
    }
    if (f + 1 < T) {              // pair tail
      unsigned pk0 = (unsigned)__shfl((int)wsrc, SLOT_IDX(f + 0));
      unsigned pk1 = (unsigned)__shfl((int)wsrc, SLOT_IDX(f + 1));
      unsigned u0 = y[(size_t)(pk0 & 0xffffu) * 64 + lane];
      unsigned u1 = y[(size_t)(pk1 & 0xffffu) * 64 + lane];
      float v0 = bf_hi(pk0);
      float v1 = bf_hi(pk1);
      aL += v0 * bf_lo(u0) + v1 * bf_lo(u1);
      aH += v0 * bf_hi(u0) + v1 * bf_hi(u1);
      f += 2;
    }
    if (f < T) {                  // single tail
      unsigned pk = (unsigned)__shfl((int)wsrc, SLOT_IDX(f));
      unsigned u = y[(size_t)(pk & 0xffffu) * 64 + lane];
      aL += bf_hi(pk) * bf_lo(u);
      aH += bf_hi(pk) * bf_hi(u);
    }
    #undef SLOT_IDX

    // overflow entries (expected 0): half 0 only
    if (half == 0) {
      int nof = *ofcnt;
      if (nof > OFCAP) nof = OFCAP;
      for (int i = 0; i < nof; ++i) {
        uint2 o = ofl[i];
        if ((int)(o.x >> 16) == row) {
          unsigned u = y[(size_t)(o.x & 0xffffu) * 64 + lane];
          float v = __int_as_float((int)o.y);
          aL += v * bf_lo(u);
          aH += v * bf_hi(u);
        }
      }
    }
  }
  part[w][lane] = make_float2(aL, aH);
  __syncthreads();

  if (half == 0 && row < N_NODES_C) {
    float2 a = part[w][lane];
    float2 b = part[w + 1][lane];
    float2 bv = *(const float2*)&bias[lane * 2];
    float2 o;
    o.x = fmaxf(a.x + b.x + bv.x, 0.0f);
    o.y = fmaxf(a.y + b.y + bv.y, 0.0f);
    *(float2*)&out[(size_t)row * D + lane * 2] = o;
  }
}

extern "C" void kernel_launch(void* const* d_in, const int* in_sizes, int n_in,
                              void* d_out, int out_size, void* d_ws, size_t ws_size,
                              hipStream_t stream) {
  const float* x = (const float*)d_in[0];
  const int* lp_rows = (const int*)d_in[1];
  const int* lp_cols = (const int*)d_in[2];
  const float* lp_vals = (const float*)d_in[3];
  const int* hp_rows = (const int*)d_in[4];
  const int* hp_cols = (const int*)d_in[5];
  const float* hp_vals = (const float*)d_in[6];
  const float* alpha_w = (const float*)d_in[7];
  const float* alpha_b = (const float*)d_in[8];
  const float* W = (const float*)d_in[9];
  const float* bias = (const float*)d_in[10];

  float* out = (float*)d_out;                      // [N, 128]
  float* alpha_out = out + (size_t)N_NODES_C * D;  // [N, 1] output tail

  char* ws = (char*)d_ws;
  unsigned* y = (unsigned*)ws;   ws += (size_t)N_NODES_C * 64 * 4;          // 12.8 MB
  float* alpha_ws = (float*)ws;  ws += 200192;
  int* rcursor = (int*)ws;       ws += (size_t)N_NODES_C * NSHARD * 4;      // 1.6 MB
  int* ofcnt = (int*)ws;         ws += 256;                                 // adjacent to rcursor
  uint2* ofl = (uint2*)ws;       ws += (size_t)OFCAP * 8;                   // 32 KB
  unsigned* pairs = (unsigned*)ws;
  ws += (size_t)N_NODES_C * NSHARD * SCAP * 4;                              // 25.6 MB

  // Dispatch 1: alpha + cursor/ofcnt zeroing (memset absorbed)
  alpha_zero_kernel<<<(N_NODES_C + 3) / 4, 256, 0, stream>>>(
      x, alpha_w, alpha_b, alpha_out, alpha_ws, rcursor, N_NODES_C);

  // Dispatch 2: block-specialized gemm || fill
  gemm_fill_kernel<<<TOTG, 256, 0, stream>>>(
      x, W, y,
      lp_rows, lp_cols, lp_vals, hp_rows, hp_cols, hp_vals,
      alpha_ws, rcursor, pairs, ofcnt, ofl, N_NODES_C);

  // Dispatch 3: gather (flattened quad-batch MLP)
  gather_kernel<<<(N_NODES_C + 1) / 2, 256, 0, stream>>>(
      rcursor, pairs, (const unsigned*)y, bias, ofcnt, ofl, out);
}